// Round 2
// baseline (282.848 us; speedup 1.0000x reference)
//
#include <hip/hip_runtime.h>

// Problem constants
#define BB 16
#define TT 2000
#define DD 512
#define OO 41          // real output classes
#define OPAD 48        // padded to 3 x 16 MFMA N-tiles
#define CN 11
#define KTOT (CN * DD) // 5632
#define MT 48          // time steps per block
#define ROWS (MT + CN - 1) // 58 feature rows staged (48 + 10 halo)
#define NTHREADS 192   // 3 waves, one 16-row M-subtile each

typedef short short8 __attribute__((ext_vector_type(8)));
typedef float f32x4 __attribute__((ext_vector_type(4)));

__device__ __forceinline__ ushort f2bf(float f) {
    unsigned u = __builtin_bit_cast(unsigned, f);
    u += 0x7FFFu + ((u >> 16) & 1u);   // RNE; inputs are finite normals
    return (ushort)(u >> 16);
}

// Convert W (41x5632 f32) -> padded bf16 (48x5632), zero pad rows.
__global__ void prep_w_kernel(const float* __restrict__ W, ushort* __restrict__ Wb) {
    int i = blockIdx.x * 256 + threadIdx.x;
    int e = i * 4;
    if (e >= OPAD * KTOT) return;
    ushort4 h;
    if (e < OO * KTOT) {
        const float4 v = *(const float4*)(W + e);
        h.x = f2bf(v.x); h.y = f2bf(v.y); h.z = f2bf(v.z); h.w = f2bf(v.w);
    } else {
        h.x = 0; h.y = 0; h.z = 0; h.w = 0;
    }
    *(ushort4*)(Wb + e) = h;
}

__device__ __forceinline__ short8 load_wf8(const float* __restrict__ Wf, int col, int kk) {
    short8 r;
    if (col < OO) {
        const float4 v0 = *(const float4*)(Wf + (size_t)col * KTOT + kk);
        const float4 v1 = *(const float4*)(Wf + (size_t)col * KTOT + kk + 4);
        r[0] = (short)f2bf(v0.x); r[1] = (short)f2bf(v0.y);
        r[2] = (short)f2bf(v0.z); r[3] = (short)f2bf(v0.w);
        r[4] = (short)f2bf(v1.x); r[5] = (short)f2bf(v1.y);
        r[6] = (short)f2bf(v1.z); r[7] = (short)f2bf(v1.w);
    } else {
        r = short8{0,0,0,0,0,0,0,0};
    }
    return r;
}

template<bool WB16>
__global__ __launch_bounds__(NTHREADS)
void conv_gemm_kernel(const float* __restrict__ F,
                      const ushort* __restrict__ Wb,
                      const float* __restrict__ Wf,
                      const float* __restrict__ bias,
                      float* __restrict__ out) {
    __shared__ ushort lds[ROWS * DD];   // 59392 B, XOR-swizzled

    const int tid = threadIdx.x;
    const int b  = blockIdx.y;
    const int t0 = blockIdx.x * MT;
    const float* Fb = F + (size_t)b * TT * DD;

    // ---- Stage 58 feature rows (clipped) as bf16 into LDS, once ----
    // row r holds F[b][clip(t0 + r - 5)][:]; swizzle byte ^= (row&7)<<4
    for (int i = tid; i < ROWS * (DD / 4); i += NTHREADS) {
        int row = i >> 7;          // DD/4 = 128 float4 per row
        int c4  = i & 127;
        int t = t0 + row - 5;
        t = t < 0 ? 0 : (t > TT - 1 ? TT - 1 : t);
        float4 v = *(const float4*)(Fb + (size_t)t * DD + c4 * 4);
        ushort4 h;
        h.x = f2bf(v.x); h.y = f2bf(v.y); h.z = f2bf(v.z); h.w = f2bf(v.w);
        int base = row * 1024 + c4 * 8;
        *(ushort4*)((char*)lds + (base ^ ((row & 7) << 4))) = h;
    }
    __syncthreads();

    const int wave = tid >> 6;
    const int lane = tid & 63;
    const int lrow = lane & 15;   // M-row within fragment / N-col for B
    const int lk   = lane >> 4;   // k-subgroup (8 contiguous k each)

    f32x4 acc0 = {0.f, 0.f, 0.f, 0.f};
    f32x4 acc1 = {0.f, 0.f, 0.f, 0.f};
    f32x4 acc2 = {0.f, 0.f, 0.f, 0.f};

    // ---- K loop: 11 frames x 16 d-chunks of 32 ----
    for (int j = 0; j < CN; ++j) {
        const int r = wave * 16 + lrow + 10 - j;      // LDS row for A fragment
        const char* arow = (const char*)lds + r * 1024;
        const int rswz = (r & 7) << 4;
        const int kbase = j * DD + lk * 8;
        #pragma unroll 4
        for (int dc = 0; dc < DD; dc += 32) {
            const int cb = (dc + lk * 8) * 2;
            short8 a = *(const short8*)(arow + (cb ^ rswz));
            short8 b0, b1, b2;
            const int kk = kbase + dc;
            if constexpr (WB16) {
                b0 = *(const short8*)(Wb + (size_t)(lrow)      * KTOT + kk);
                b1 = *(const short8*)(Wb + (size_t)(16 + lrow) * KTOT + kk);
                b2 = *(const short8*)(Wb + (size_t)(32 + lrow) * KTOT + kk);
            } else {
                b0 = load_wf8(Wf, lrow, kk);
                b1 = load_wf8(Wf, 16 + lrow, kk);
                b2 = load_wf8(Wf, 32 + lrow, kk);
            }
            acc0 = __builtin_amdgcn_mfma_f32_16x16x32_bf16(a, b0, acc0, 0, 0, 0);
            acc1 = __builtin_amdgcn_mfma_f32_16x16x32_bf16(a, b1, acc1, 0, 0, 0);
            acc2 = __builtin_amdgcn_mfma_f32_16x16x32_bf16(a, b2, acc2, 0, 0, 0);
        }
    }

    // ---- Epilogue: C[row=(lane>>4)*4+q][col=lane&15], add bias, masked store ----
    const float bias0 = bias[lrow];            // cols 0..15
    const float bias1 = bias[16 + lrow];       // cols 16..31
    const float bias2 = (32 + lrow < OO) ? bias[32 + lrow] : 0.f;  // cols 32..40
    const int tbase = t0 + wave * 16 + lk * 4;
    float* outb = out + (size_t)b * TT * OO;
    #pragma unroll
    for (int q = 0; q < 4; ++q) {
        const int t = tbase + q;
        if (t < TT) {
            float* po = outb + (size_t)t * OO;
            po[lrow]      = acc0[q] + bias0;
            po[16 + lrow] = acc1[q] + bias1;
            if (32 + lrow < OO) po[32 + lrow] = acc2[q] + bias2;
        }
    }
}

extern "C" void kernel_launch(void* const* d_in, const int* in_sizes, int n_in,
                              void* d_out, int out_size, void* d_ws, size_t ws_size,
                              hipStream_t stream) {
    const float* F    = (const float*)d_in[0];
    const float* W    = (const float*)d_in[1];
    const float* bias = (const float*)d_in[2];
    float* out = (float*)d_out;

    const dim3 grid((TT + MT - 1) / MT, BB);   // 42 x 16 = 672 blocks

    const size_t wb_bytes = (size_t)OPAD * KTOT * sizeof(ushort);  // 540672
    if (ws_size >= wb_bytes) {
        ushort* Wb = (ushort*)d_ws;
        const int prep_elems4 = OPAD * KTOT / 4;
        prep_w_kernel<<<(prep_elems4 + 255) / 256, 256, 0, stream>>>(W, Wb);
        conv_gemm_kernel<true><<<grid, NTHREADS, 0, stream>>>(F, Wb, W, bias, out);
    } else {
        conv_gemm_kernel<false><<<grid, NTHREADS, 0, stream>>>(F, nullptr, W, bias, out);
    }
}

// Round 3
// 162.529 us; speedup vs baseline: 1.7403x; 1.7403x over previous
//
#include <hip/hip_runtime.h>

// Problem constants
#define BB 16
#define TT 2000
#define DD 512
#define OO 41          // real output classes
#define OPAD 48        // padded to 3 x 16 MFMA N-tiles
#define CN 11
#define KTOT (CN * DD) // 5632
#define NITER (CN * 16) // 176 K-iterations of 32
#define MT 64          // time steps per block
#define ROWS (MT + CN - 1) // 74 feature rows staged (64 + 10 halo)
#define NTHREADS 256   // 4 waves, one 16-row M-subtile each

typedef short short8 __attribute__((ext_vector_type(8)));
typedef float f32x4 __attribute__((ext_vector_type(4)));

__device__ __forceinline__ ushort f2bf(float f) {
    unsigned u = __builtin_bit_cast(unsigned, f);
    u += 0x7FFFu + ((u >> 16) & 1u);   // RNE; inputs are finite normals
    return (ushort)(u >> 16);
}

// Relayout W (41x5632 f32) into MFMA-fragment-major bf16:
// chunk index c = it*3 + nblk  (it = j*16 + dc16, 176 iters; nblk 0..2)
// element offset = (c*64 + lane)*8 ; value = W[nblk*16 + (lane&15)]
//                                            [j*512 + dc16*32 + (lane>>4)*8 + i]
// Inner-loop B-load then is a fully coalesced 16B/lane sequential stream.
__global__ void prep_w_kernel(const float* __restrict__ W, ushort* __restrict__ Wf) {
    int tid = blockIdx.x * 256 + threadIdx.x;
    if (tid >= NITER * 3 * 64) return;
    int lane = tid & 63;
    int rest = tid >> 6;          // it*3 + nblk
    int nblk = rest % 3;
    int it   = rest / 3;
    int j    = it >> 4;
    int dc16 = it & 15;
    int row  = nblk * 16 + (lane & 15);
    int col  = j * DD + dc16 * 32 + (lane >> 4) * 8;
    short8 h = short8{0,0,0,0,0,0,0,0};
    if (row < OO) {
        const float* p = W + (size_t)row * KTOT + col;
        #pragma unroll
        for (int i = 0; i < 8; ++i) h[i] = (short)f2bf(p[i]);
    }
    *(short8*)(Wf + (size_t)tid * 8) = h;
}

__device__ __forceinline__ short8 load_wf8(const float* __restrict__ Wf, int col, int kk) {
    short8 r;
    if (col < OO) {
        const float4 v0 = *(const float4*)(Wf + (size_t)col * KTOT + kk);
        const float4 v1 = *(const float4*)(Wf + (size_t)col * KTOT + kk + 4);
        r[0] = (short)f2bf(v0.x); r[1] = (short)f2bf(v0.y);
        r[2] = (short)f2bf(v0.z); r[3] = (short)f2bf(v0.w);
        r[4] = (short)f2bf(v1.x); r[5] = (short)f2bf(v1.y);
        r[6] = (short)f2bf(v1.z); r[7] = (short)f2bf(v1.w);
    } else {
        r = short8{0,0,0,0,0,0,0,0};
    }
    return r;
}

template<bool WB16>
__global__ __launch_bounds__(NTHREADS)
void conv_gemm_kernel(const float* __restrict__ F,
                      const ushort* __restrict__ Wfrag,
                      const float* __restrict__ Wf,
                      const float* __restrict__ bias,
                      float* __restrict__ out) {
    __shared__ ushort lds[ROWS * DD];   // 75776 B, XOR-swizzled -> 2 blocks/CU

    const int tid = threadIdx.x;
    const int b  = blockIdx.y;
    const int t0 = blockIdx.x * MT;
    const float* Fb = F + (size_t)b * TT * DD;

    // ---- Stage 74 feature rows (clipped) as bf16 into LDS, once ----
    // row r holds F[b][clip(t0 + r - 5)][:]; swizzle byte ^= (row&7)<<4
    for (int i = tid; i < ROWS * (DD / 4); i += NTHREADS) {
        int row = i >> 7;          // DD/4 = 128 float4 per row
        int c4  = i & 127;
        int t = t0 + row - 5;
        t = t < 0 ? 0 : (t > TT - 1 ? TT - 1 : t);
        float4 v = *(const float4*)(Fb + (size_t)t * DD + c4 * 4);
        ushort4 h;
        h.x = f2bf(v.x); h.y = f2bf(v.y); h.z = f2bf(v.z); h.w = f2bf(v.w);
        int base = row * 1024 + c4 * 8;
        *(ushort4*)((char*)lds + (base ^ ((row & 7) << 4))) = h;
    }
    __syncthreads();

    const int wave = tid >> 6;
    const int lane = tid & 63;
    const int lrow = lane & 15;   // M-row within fragment / N-col for B
    const int lk   = lane >> 4;   // k-subgroup (8 contiguous k each)

    f32x4 acc0 = {0.f, 0.f, 0.f, 0.f};
    f32x4 acc1 = {0.f, 0.f, 0.f, 0.f};
    f32x4 acc2 = {0.f, 0.f, 0.f, 0.f};

    const ushort* wlane = Wfrag + (size_t)lane * 8;   // + it*1536 + nblk*512

    // ---- K loop: 11 frames x 16 d-chunks of 32 ----
    for (int j = 0; j < CN; ++j) {
        const int r = wave * 16 + lrow + 10 - j;      // LDS row for A fragment
        const char* arow = (const char*)lds + r * 1024;
        const int rswz = (r & 7) << 4;
        #pragma unroll 4
        for (int dc = 0; dc < DD; dc += 32) {
            const int cb = (dc + lk * 8) * 2;
            short8 a = *(const short8*)(arow + (cb ^ rswz));
            short8 b0, b1, b2;
            if constexpr (WB16) {
                const ushort* wp = wlane + (size_t)(j * 16 + (dc >> 5)) * 1536;
                b0 = *(const short8*)(wp);
                b1 = *(const short8*)(wp + 512);
                b2 = *(const short8*)(wp + 1024);
            } else {
                const int kk = j * DD + dc + lk * 8;
                b0 = load_wf8(Wf, lrow, kk);
                b1 = load_wf8(Wf, 16 + lrow, kk);
                b2 = load_wf8(Wf, 32 + lrow, kk);
            }
            acc0 = __builtin_amdgcn_mfma_f32_16x16x32_bf16(a, b0, acc0, 0, 0, 0);
            acc1 = __builtin_amdgcn_mfma_f32_16x16x32_bf16(a, b1, acc1, 0, 0, 0);
            acc2 = __builtin_amdgcn_mfma_f32_16x16x32_bf16(a, b2, acc2, 0, 0, 0);
        }
    }

    // ---- Epilogue: C[row=(lane>>4)*4+q][col=lane&15], add bias, masked store ----
    const float bias0 = bias[lrow];            // cols 0..15
    const float bias1 = bias[16 + lrow];       // cols 16..31
    const float bias2 = (32 + lrow < OO) ? bias[32 + lrow] : 0.f;  // cols 32..40
    const int tbase = t0 + wave * 16 + lk * 4;
    float* outb = out + (size_t)b * TT * OO;
    #pragma unroll
    for (int q = 0; q < 4; ++q) {
        const int t = tbase + q;
        if (t < TT) {
            float* po = outb + (size_t)t * OO;
            po[lrow]      = acc0[q] + bias0;
            po[16 + lrow] = acc1[q] + bias1;
            if (32 + lrow < OO) po[32 + lrow] = acc2[q] + bias2;
        }
    }
}

extern "C" void kernel_launch(void* const* d_in, const int* in_sizes, int n_in,
                              void* d_out, int out_size, void* d_ws, size_t ws_size,
                              hipStream_t stream) {
    const float* F    = (const float*)d_in[0];
    const float* W    = (const float*)d_in[1];
    const float* bias = (const float*)d_in[2];
    float* out = (float*)d_out;

    const dim3 grid((TT + MT - 1) / MT, BB);   // 32 x 16 = 512 blocks

    const size_t wb_bytes = (size_t)NITER * 3 * 64 * 8 * sizeof(ushort);  // 540672
    if (ws_size >= wb_bytes) {
        ushort* Wb = (ushort*)d_ws;
        const int prep_threads = NITER * 3 * 64;   // 33792
        prep_w_kernel<<<(prep_threads + 255) / 256, 256, 0, stream>>>(W, Wb);
        conv_gemm_kernel<true><<<grid, NTHREADS, 0, stream>>>(F, Wb, W, bias, out);
    } else {
        conv_gemm_kernel<false><<<grid, NTHREADS, 0, stream>>>(F, nullptr, W, bias, out);
    }
}